// Round 1
// baseline (526.588 us; speedup 1.0000x reference)
//
#include <hip/hip_runtime.h>
#include <math.h>

// Problem constants (match setup_inputs)
#define BATCH 8
#define T_LEN 25000
#define NW    1000
#define WS    25
#define D0    256
#define H     128

typedef __bf16 bf16;
typedef bf16 bf16x8 __attribute__((ext_vector_type(8)));
typedef bf16 bf16x4 __attribute__((ext_vector_type(4)));
typedef float f32x4 __attribute__((ext_vector_type(4)));

// tanh-form GELU via v_exp_f32. |err| <= ~3e-3 absolute.
__device__ __forceinline__ float gelu_fast(float x) {
    float y = 0.7978845608f * x * (1.0f + 0.044715f * x * x);
    float e = __expf(2.0f * y);
    float t = 1.0f - 2.0f * __builtin_amdgcn_rcpf(e + 1.0f);
    return 0.5f * x * (1.0f + t);
}

// ---------------------------------------------------------------------------
// Weight repack (16x16x32 A-fragments, R3-verified):
//   dst[ ((k*KSn + ks)*8 + mt)*512 + lane*8 + j ]
//     = w[ co=mt*16+(lane&15) ][ ci=ks*32+(lane>>4)*8+j ][ k ]
// ---------------------------------------------------------------------------
__device__ __forceinline__ void repack_one(const float* __restrict__ w,
                                           bf16* __restrict__ dst, int idx,
                                           int Cin, int K, int KSn) {
    int j    = idx & 7;
    int lane = (idx >> 3) & 63;
    int mt   = (idx >> 9) & 7;
    int ks   = (idx >> 12) % KSn;
    int k    = idx / (4096 * KSn);
    int co = mt * 16 + (lane & 15);
    int ci = ks * 32 + (lane >> 4) * 8 + j;
    dst[idx] = (bf16)w[(co * Cin + ci) * K + k];
}

__global__ void prep_kernel(const float* __restrict__ c0w, const float* __restrict__ c1w,
                            const float* __restrict__ c2w, const float* __restrict__ hw1,
                            bf16* __restrict__ p0, bf16* __restrict__ p1,
                            bf16* __restrict__ p2, bf16* __restrict__ hw1b) {
    int t = blockIdx.x * 256 + threadIdx.x;
    if (t < 229376) {
        repack_one(c0w, p0, t, 256, 7, 8);
    } else if (t < 311296) {
        repack_one(c1w, p1, t - 229376, 128, 5, 4);
    } else if (t < 393216) {
        repack_one(c2w, p2, t - 311296, 128, 5, 4);
    } else if (t < 409600) {
        int i = t - 393216;
        hw1b[i] = (bf16)hw1[i];
    }
}

// ---------------------------------------------------------------------------
// Fused critic, W=4 windows/block, 512 threads = 8 waves.
// NEW partition (occupancy fix): wave wv -> (win = wv&3, mtg = wv>>2).
// Each wave: 4 co m-tiles (mt = mtg*4+i) x 1 window x 2 n-tiles -> 8 f32x4 acc.
// Per (k,ks): 2 LDS B-reads + 4 L2 A-loads feed 8 MFMAs (B-bytes/MFMA 512->256;
// per-block ds_read_b128 count halves). Weights (786 KB) stay L2-resident.
// 16 waves/CU = 4 waves/SIMD (was 2) -> LDS/MFMA/VALU pipes can overlap.
//
// LDS (74848 B -> 2 blocks/CU, 150528 <= 163840):
//  xT  bf16[134][264] @0     win j rows 31j..31j+30 (l+3), tail rows 124..133
//                            garbage-only (fed to discarded cols). 70752 B
//  a1T bf16[123][136] @0     OVERLAY (xT dead after conv0); win j row = l+2+29j
//  a2T bf16[123][136] @33456 also inside xT region (33456+33456 <= 70752)
//  feat float[512]    @70752 (128 per window)
//  hbuf float[512]    @72800
// Bounds audit (byte offsets, incl. garbage-column over-reads):
//  conv0 reads  <= 130*528+480    = 69120 < 70752  OK
//  conv1 reads  <= 122*272+240    = 33424 < 33456 (a1T size) OK
//  conv2 reads  <= 33456+33424    = 66880 < 70752  OK
//  valid epilogue writes: a1T/a2T rows <= 113 -> disjoint from feat/hbuf.
// __launch_bounds__(512,4): 128-reg cap. Safe now: acc = 8 f32x4 = 32 VGPRs
// (R4's spill was with 16 f32x4 = 64 acc VGPRs under a 128 cap).
// ---------------------------------------------------------------------------
#define XT_LD 264
#define A_LD  136
#define OFF_A2   33456
#define OFF_FEAT 70752
#define OFF_H    72800
#define SMEM_BYTES 74848

__global__ __launch_bounds__(512, 4)
void critic_kernel(const float* __restrict__ lat,
                   const bf16* __restrict__ p0, const float* __restrict__ b0,
                   const bf16* __restrict__ p1, const float* __restrict__ b1,
                   const bf16* __restrict__ p2, const float* __restrict__ b2,
                   const bf16* __restrict__ hw1b, const float* __restrict__ hb1,
                   const float* __restrict__ hw2, const float* __restrict__ hb2,
                   float* __restrict__ scores_tmp) {
    __shared__ __align__(16) char smem[SMEM_BYTES];
    bf16  (*xT)[XT_LD]  = (bf16(*)[XT_LD])smem;
    bf16  (*a1T)[A_LD]  = (bf16(*)[A_LD])smem;            // overlays xT after conv0
    bf16  (*a2T)[A_LD]  = (bf16(*)[A_LD])(smem + OFF_A2); // ditto
    float* feat = (float*)(smem + OFF_FEAT);
    float* hbuf = (float*)(smem + OFF_H);

    const int tid = threadIdx.x;
    const int bx  = blockIdx.x;
    const int b   = bx / (NW / 4);
    const int wi  = bx % (NW / 4);
    const int w0  = 4 * wi;

    // ---- stage 4 adjacent windows: 100*256 floats = 6400 float4 ----
    {
        const float4* src4 = (const float4*)(lat + ((size_t)b * T_LEN + (size_t)w0 * WS) * D0);
        #pragma unroll
        for (int it = 0; it < 13; ++it) {
            int g = tid + it * 512;
            if (g < 6400) {
                int l = g >> 6, c0 = (g & 63) * 4;
                int win = l / 25, lr = l - win * 25;
                int r = 31 * win + lr + 3;
                float4 v = src4[g];
                bf16x4 o = {(bf16)v.x, (bf16)v.y, (bf16)v.z, (bf16)v.w};
                *(bf16x4*)&xT[r][c0] = o;
            }
        }
        // zero xT pad rows 31j+{0,1,2,28,29,30}, j=0..3: 24 rows x 64 bf16x4
        bf16x4 z4 = {};
        #pragma unroll
        for (int it = 0; it < 3; ++it) {
            int i = tid + it * 512;
            int rr = i >> 6, c0 = (i & 63) * 4;
            int j = rr / 6, t6 = rr - 6 * j;
            int r = 31 * j + ((t6 < 3) ? t6 : t6 + 25);
            *(bf16x4*)&xT[r][c0] = z4;
        }
    }
    __syncthreads();

    const int lane = tid & 63, wv = tid >> 6;
    const int win = wv & 3, mtg = wv >> 2;        // wave = (window, co-half)
    const int m = lane & 15, q = lane >> 4;
    const bf16* xb  = &xT[m][q * 8];
    const bf16* a1b = &a1T[m][q * 8];

    // ================= conv0: Cin=256 (8 K-steps), K=7, pad=3 =================
    f32x4 acc[4][2] = {};
    {
        const bf16x8* A = (const bf16x8*)p0 + (size_t)mtg * 256 + lane;
        #pragma unroll
        for (int k = 0; k < 7; ++k) {
            #pragma unroll
            for (int ks = 0; ks < 8; ++ks) {
                int f = (k * 8 + ks) * 512;
                bf16x8 a0 = A[f], a1 = A[f + 64], a2 = A[f + 128], a3 = A[f + 192];
                const bf16* pB = xb + (k + 31 * win) * XT_LD + ks * 32;
                bf16x8 bb0 = *(const bf16x8*)(pB);
                bf16x8 bb1 = *(const bf16x8*)(pB + 16 * XT_LD);
                acc[0][0] = __builtin_amdgcn_mfma_f32_16x16x32_bf16(a0, bb0, acc[0][0], 0, 0, 0);
                acc[0][1] = __builtin_amdgcn_mfma_f32_16x16x32_bf16(a0, bb1, acc[0][1], 0, 0, 0);
                acc[1][0] = __builtin_amdgcn_mfma_f32_16x16x32_bf16(a1, bb0, acc[1][0], 0, 0, 0);
                acc[1][1] = __builtin_amdgcn_mfma_f32_16x16x32_bf16(a1, bb1, acc[1][1], 0, 0, 0);
                acc[2][0] = __builtin_amdgcn_mfma_f32_16x16x32_bf16(a2, bb0, acc[2][0], 0, 0, 0);
                acc[2][1] = __builtin_amdgcn_mfma_f32_16x16x32_bf16(a2, bb1, acc[2][1], 0, 0, 0);
                acc[3][0] = __builtin_amdgcn_mfma_f32_16x16x32_bf16(a3, bb0, acc[3][0], 0, 0, 0);
                acc[3][1] = __builtin_amdgcn_mfma_f32_16x16x32_bf16(a3, bb1, acc[3][1], 0, 0, 0);
            }
        }
    }
    __syncthreads();   // xT dead; region reused for a1T/a2T
    // zero a1T+a2T pad rows 29j+{0,1,27,28}: 16 rows x 32 bf16x4 each
    {
        bf16x4 z4 = {};
        #pragma unroll
        for (int it = 0; it < 2; ++it) {
            int i = tid + it * 512;
            int arr = i >> 9, rr = (i >> 5) & 15, c0 = (i & 31) * 4;
            int j = rr >> 2, t4 = rr & 3;
            int r = 29 * j + ((t4 < 2) ? t4 : t4 + 25);
            if (arr == 0) *(bf16x4*)&a1T[r][c0] = z4;
            else          *(bf16x4*)&a2T[r][c0] = z4;
        }
    }
    // conv0 epilogue: gelu -> a1T  (C/D: col=nt*16+m, row=q*4+r within tile)
    #pragma unroll
    for (int i = 0; i < 4; ++i) {
        int co0 = (mtg * 4 + i) * 16 + q * 4;
        f32x4 bv = *(const f32x4*)&b0[co0];
        #pragma unroll
        for (int nt = 0; nt < 2; ++nt) {
            int l = nt * 16 + m;
            if (l < 25) {
                bf16x4 v;
                #pragma unroll
                for (int r = 0; r < 4; ++r)
                    v[r] = (bf16)gelu_fast(acc[i][nt][r] + bv[r]);
                *(bf16x4*)&a1T[l + 2 + 29 * win][co0] = v;
            }
        }
    }
    __syncthreads();

    // ================= conv1: Cin=128 (4 K-steps), K=5, pad=2 =================
    f32x4 c1[4][2] = {};
    {
        const bf16x8* A = (const bf16x8*)p1 + (size_t)mtg * 256 + lane;
        #pragma unroll
        for (int k = 0; k < 5; ++k) {
            #pragma unroll
            for (int ks = 0; ks < 4; ++ks) {
                int f = (k * 4 + ks) * 512;
                bf16x8 a0 = A[f], a1 = A[f + 64], a2 = A[f + 128], a3 = A[f + 192];
                const bf16* pB = a1b + (k + 29 * win) * A_LD + ks * 32;
                bf16x8 bb0 = *(const bf16x8*)(pB);
                bf16x8 bb1 = *(const bf16x8*)(pB + 16 * A_LD);
                c1[0][0] = __builtin_amdgcn_mfma_f32_16x16x32_bf16(a0, bb0, c1[0][0], 0, 0, 0);
                c1[0][1] = __builtin_amdgcn_mfma_f32_16x16x32_bf16(a0, bb1, c1[0][1], 0, 0, 0);
                c1[1][0] = __builtin_amdgcn_mfma_f32_16x16x32_bf16(a1, bb0, c1[1][0], 0, 0, 0);
                c1[1][1] = __builtin_amdgcn_mfma_f32_16x16x32_bf16(a1, bb1, c1[1][1], 0, 0, 0);
                c1[2][0] = __builtin_amdgcn_mfma_f32_16x16x32_bf16(a2, bb0, c1[2][0], 0, 0, 0);
                c1[2][1] = __builtin_amdgcn_mfma_f32_16x16x32_bf16(a2, bb1, c1[2][1], 0, 0, 0);
                c1[3][0] = __builtin_amdgcn_mfma_f32_16x16x32_bf16(a3, bb0, c1[3][0], 0, 0, 0);
                c1[3][1] = __builtin_amdgcn_mfma_f32_16x16x32_bf16(a3, bb1, c1[3][1], 0, 0, 0);
            }
        }
    }
    // epilogue -> a2T (valid conv1 reads stay below a2T; garbage discarded)
    #pragma unroll
    for (int i = 0; i < 4; ++i) {
        int co0 = (mtg * 4 + i) * 16 + q * 4;
        f32x4 bv = *(const f32x4*)&b1[co0];
        #pragma unroll
        for (int nt = 0; nt < 2; ++nt) {
            int l = nt * 16 + m;
            if (l < 25) {
                bf16x4 v;
                #pragma unroll
                for (int r = 0; r < 4; ++r)
                    v[r] = (bf16)gelu_fast(c1[i][nt][r] + bv[r]);
                *(bf16x4*)&a2T[l + 2 + 29 * win][co0] = v;
            }
        }
    }
    __syncthreads();

    // ================= conv2: Cin=128 (4 K-steps), K=5, pad=2 =================
    f32x4 c2[4][2] = {};
    {
        const bf16* a2b = &a2T[m][q * 8];
        const bf16x8* A = (const bf16x8*)p2 + (size_t)mtg * 256 + lane;
        #pragma unroll
        for (int k = 0; k < 5; ++k) {
            #pragma unroll
            for (int ks = 0; ks < 4; ++ks) {
                int f = (k * 4 + ks) * 512;
                bf16x8 a0 = A[f], a1 = A[f + 64], a2 = A[f + 128], a3 = A[f + 192];
                const bf16* pB = a2b + (k + 29 * win) * A_LD + ks * 32;
                bf16x8 bb0 = *(const bf16x8*)(pB);
                bf16x8 bb1 = *(const bf16x8*)(pB + 16 * A_LD);
                c2[0][0] = __builtin_amdgcn_mfma_f32_16x16x32_bf16(a0, bb0, c2[0][0], 0, 0, 0);
                c2[0][1] = __builtin_amdgcn_mfma_f32_16x16x32_bf16(a0, bb1, c2[0][1], 0, 0, 0);
                c2[1][0] = __builtin_amdgcn_mfma_f32_16x16x32_bf16(a1, bb0, c2[1][0], 0, 0, 0);
                c2[1][1] = __builtin_amdgcn_mfma_f32_16x16x32_bf16(a1, bb1, c2[1][1], 0, 0, 0);
                c2[2][0] = __builtin_amdgcn_mfma_f32_16x16x32_bf16(a2, bb0, c2[2][0], 0, 0, 0);
                c2[2][1] = __builtin_amdgcn_mfma_f32_16x16x32_bf16(a2, bb1, c2[2][1], 0, 0, 0);
                c2[3][0] = __builtin_amdgcn_mfma_f32_16x16x32_bf16(a3, bb0, c2[3][0], 0, 0, 0);
                c2[3][1] = __builtin_amdgcn_mfma_f32_16x16x32_bf16(a3, bb1, c2[3][1], 0, 0, 0);
            }
        }
    }
    // ===== register pooling: gelu + shuffle-reduce over l (lane bits 0-3) =====
    #pragma unroll
    for (int i = 0; i < 4; ++i) {
        int co0 = (mtg * 4 + i) * 16 + q * 4;
        f32x4 bv = *(const f32x4*)&b2[co0];
        f32x4 pool;
        #pragma unroll
        for (int r = 0; r < 4; ++r) {
            float s  = gelu_fast(c2[i][0][r] + bv[r]);       // l = m < 25
            float g1 = gelu_fast(c2[i][1][r] + bv[r]);       // l = 16+m
            s += (m < 9) ? g1 : 0.0f;
            s += __shfl_xor(s, 1);
            s += __shfl_xor(s, 2);
            s += __shfl_xor(s, 4);
            s += __shfl_xor(s, 8);
            pool[r] = s * 0.04f;
        }
        if (m == 0) *(f32x4*)&feat[win * 128 + co0] = pool;
    }
    __syncthreads();

    // ===== head: 512 dots of length 128; one per thread =====
    {
        int wb = tid >> 7, co = tid & 127;
        const bf16x8* row = (const bf16x8*)(hw1b + co * H);
        const float* f0 = feat + wb * 128;
        float a0h = hb1[co];
        #pragma unroll
        for (int jv = 0; jv < 16; ++jv) {
            bf16x8 w8 = row[jv];
            #pragma unroll
            for (int u = 0; u < 8; ++u)
                a0h += (float)w8[u] * f0[jv * 8 + u];
        }
        hbuf[wb * 128 + co] = gelu_fast(a0h);
    }
    __syncthreads();

    if (tid < 256) {
        int win2 = tid >> 6, j = tid & 63;    // 4 waves -> 4 windows
        const float* hb = hbuf + win2 * 128;
        float p = hw2[j] * hb[j] + hw2[j + 64] * hb[j + 64];
        #pragma unroll
        for (int off = 32; off > 0; off >>= 1) p += __shfl_down(p, off);
        if (j == 0) {
            float z = p + hb2[0];
            scores_tmp[b * NW + w0 + win2] = 5.0f / (1.0f + expf(-z));
        }
    }
}

// ---------------------------------------------------------------------------
__global__ void finalize_kernel(const float* __restrict__ tmp, float* __restrict__ out) {
    int w = blockIdx.x * 256 + threadIdx.x;
    if (w < NW) {
        float s = 0.0f;
        #pragma unroll
        for (int b = 0; b < BATCH; ++b) s += tmp[b * NW + w];
        s *= 0.125f;
        out[w] = s;
        out[NW + w] = (s < 3.5f) ? 1.0f : 0.0f;
    }
}

// ---------------------------------------------------------------------------
extern "C" void kernel_launch(void* const* d_in, const int* in_sizes, int n_in,
                              void* d_out, int out_size, void* d_ws, size_t ws_size,
                              hipStream_t stream) {
    const float* lat  = (const float*)d_in[0];
    const float* c0w  = (const float*)d_in[1];
    const float* c0b  = (const float*)d_in[2];
    const float* c1w  = (const float*)d_in[3];
    const float* c1b  = (const float*)d_in[4];
    const float* c2w  = (const float*)d_in[5];
    const float* c2b  = (const float*)d_in[6];
    const float* hw1  = (const float*)d_in[7];
    const float* hb1  = (const float*)d_in[8];
    const float* hw2  = (const float*)d_in[9];
    const float* hb2  = (const float*)d_in[10];

    // workspace layout
    bf16* p0   = (bf16*)d_ws;                                 // 458752 B
    bf16* p1   = (bf16*)((char*)d_ws + 458752);               // 163840 B
    bf16* p2   = (bf16*)((char*)d_ws + 622592);               // 163840 B
    bf16* hw1b = (bf16*)((char*)d_ws + 786432);               //  32768 B
    float* tmp = (float*)((char*)d_ws + 819200);              //  32000 B

    prep_kernel<<<1600, 256, 0, stream>>>(c0w, c1w, c2w, hw1, p0, p1, p2, hw1b);
    critic_kernel<<<BATCH * (NW / 4), 512, 0, stream>>>(lat, p0, c0b, p1, c1b, p2, c2b,
                                                        hw1b, hb1, hw2, hb2, tmp);
    finalize_kernel<<<4, 256, 0, stream>>>(tmp, (float*)d_out);
}

// Round 2
// 510.962 us; speedup vs baseline: 1.0306x; 1.0306x over previous
//
#include <hip/hip_runtime.h>
#include <math.h>

// Problem constants (match setup_inputs)
#define BATCH 8
#define T_LEN 25000
#define NW    1000
#define WS    25
#define D0    256
#define H     128

typedef __bf16 bf16;
typedef bf16 bf16x8 __attribute__((ext_vector_type(8)));
typedef bf16 bf16x4 __attribute__((ext_vector_type(4)));
typedef float f32x4 __attribute__((ext_vector_type(4)));

// tanh-form GELU via v_exp_f32. |err| <= ~3e-3 absolute.
__device__ __forceinline__ float gelu_fast(float x) {
    float y = 0.7978845608f * x * (1.0f + 0.044715f * x * x);
    float e = __expf(2.0f * y);
    float t = 1.0f - 2.0f * __builtin_amdgcn_rcpf(e + 1.0f);
    return 0.5f * x * (1.0f + t);
}

// ---------------------------------------------------------------------------
// Weight repack (16x16x32 A-fragments, R3-verified):
//   dst[ ((k*KSn + ks)*8 + mt)*512 + lane*8 + j ]
//     = w[ co=mt*16+(lane&15) ][ ci=ks*32+(lane>>4)*8+j ][ k ]
// ---------------------------------------------------------------------------
__device__ __forceinline__ void repack_one(const float* __restrict__ w,
                                           bf16* __restrict__ dst, int idx,
                                           int Cin, int K, int KSn) {
    int j    = idx & 7;
    int lane = (idx >> 3) & 63;
    int mt   = (idx >> 9) & 7;
    int ks   = (idx >> 12) % KSn;
    int k    = idx / (4096 * KSn);
    int co = mt * 16 + (lane & 15);
    int ci = ks * 32 + (lane >> 4) * 8 + j;
    dst[idx] = (bf16)w[(co * Cin + ci) * K + k];
}

__global__ void prep_kernel(const float* __restrict__ c0w, const float* __restrict__ c1w,
                            const float* __restrict__ c2w, const float* __restrict__ hw1,
                            bf16* __restrict__ p0, bf16* __restrict__ p1,
                            bf16* __restrict__ p2, bf16* __restrict__ hw1b) {
    int t = blockIdx.x * 256 + threadIdx.x;
    if (t < 229376) {
        repack_one(c0w, p0, t, 256, 7, 8);
    } else if (t < 311296) {
        repack_one(c1w, p1, t - 229376, 128, 5, 4);
    } else if (t < 393216) {
        repack_one(c2w, p2, t - 311296, 128, 5, 4);
    } else if (t < 409600) {
        int i = t - 393216;
        hw1b[i] = (bf16)hw1[i];
    }
}

// ---------------------------------------------------------------------------
// Fused critic, W=4 windows/block, 512 threads = 8 waves.
// Wave partition: wv -> (win = wv&3, mtg = wv>>2); each wave 4 m-tiles x 1 win.
//
// R2 change (latency theory): R0->R1 showed duration invariant to occupancy
// doubling -> limiter is per-step exposed global-A latency (compiler at 64
// VGPR does no cross-step prefetch; all waves stall in lockstep). Fix:
// explicit SW pipeline in conv_phase<> — A prefetched 2 steps ahead (3 bufs),
// B (LDS) 1 step ahead (2 bufs), phase barrier moved AFTER first A-issue so
// cold-start latency hides under the barrier drain. Step (k,ks) become
// compile-time -> ds_read offsets fold to immediates.
//
// LDS (74848 B -> 2 blocks/CU): layout + bounds audit unchanged from R1
// (R3-verified): xT[134][264]@0 (70752 B), a1T[123][136]@0 overlay,
// a2T@33456, feat@70752, hbuf@72800.
// __launch_bounds__(512,4): 128-reg cap. MUST stay <=128 (VGPR cliff at 128
// would drop to 1 block/CU). Pipeline regs: a[3][4]=48 + bb[2][2]=16 +
// acc=32 ≈ 110 total.
// ---------------------------------------------------------------------------
#define XT_LD 264
#define A_LD  136
#define OFF_A2   33456
#define OFF_FEAT 70752
#define OFF_H    72800
#define SMEM_BYTES 74848

// Software-pipelined conv phase. A: global (L2-resident weights), depth-2
// prefetch. B: LDS, depth-1 prefetch. Does the phase-entry __syncthreads()
// internally (after issuing the first A loads).
template<int NS, int KSN, int LD>
__device__ __forceinline__ void conv_phase(const bf16x8* __restrict__ A,
                                           const bf16* __restrict__ bbase,
                                           int rowoff, f32x4 (&acc)[4][2]) {
    bf16x8 a[3][4];
    bf16x8 bb[2][2];
    // issue A prefetch for steps 0,1 BEFORE the barrier (A is global; the
    // barrier only publishes the LDS B buffer) -> latency hides in the drain
    #pragma unroll
    for (int u = 0; u < 4; ++u) a[0][u] = A[u * 64];
    #pragma unroll
    for (int u = 0; u < 4; ++u) a[1][u] = A[512 + u * 64];
    __syncthreads();
    {
        const bf16* pB = bbase + rowoff * LD;           // s=0: k=0, ks=0
        bb[0][0] = *(const bf16x8*)pB;
        bb[0][1] = *(const bf16x8*)(pB + 16 * LD);
    }
    #pragma unroll
    for (int s = 0; s < NS; ++s) {
        const int cur = s & 1, nxt = cur ^ 1;
        const int ap = s % 3;
        if (s + 2 < NS) {                                // A prefetch, dist 2
            const int ai = (s + 2) % 3;
            const int f = (s + 2) * 512;
            #pragma unroll
            for (int u = 0; u < 4; ++u) a[ai][u] = A[f + u * 64];
        }
        if (s + 1 < NS) {                                // B prefetch, dist 1
            const int k1 = (s + 1) / KSN, ks1 = (s + 1) % KSN;
            const bf16* pB = bbase + (k1 + rowoff) * LD + ks1 * 32;
            bb[nxt][0] = *(const bf16x8*)pB;
            bb[nxt][1] = *(const bf16x8*)(pB + 16 * LD);
        }
        acc[0][0] = __builtin_amdgcn_mfma_f32_16x16x32_bf16(a[ap][0], bb[cur][0], acc[0][0], 0, 0, 0);
        acc[0][1] = __builtin_amdgcn_mfma_f32_16x16x32_bf16(a[ap][0], bb[cur][1], acc[0][1], 0, 0, 0);
        acc[1][0] = __builtin_amdgcn_mfma_f32_16x16x32_bf16(a[ap][1], bb[cur][0], acc[1][0], 0, 0, 0);
        acc[1][1] = __builtin_amdgcn_mfma_f32_16x16x32_bf16(a[ap][1], bb[cur][1], acc[1][1], 0, 0, 0);
        acc[2][0] = __builtin_amdgcn_mfma_f32_16x16x32_bf16(a[ap][2], bb[cur][0], acc[2][0], 0, 0, 0);
        acc[2][1] = __builtin_amdgcn_mfma_f32_16x16x32_bf16(a[ap][2], bb[cur][1], acc[2][1], 0, 0, 0);
        acc[3][0] = __builtin_amdgcn_mfma_f32_16x16x32_bf16(a[ap][3], bb[cur][0], acc[3][0], 0, 0, 0);
        acc[3][1] = __builtin_amdgcn_mfma_f32_16x16x32_bf16(a[ap][3], bb[cur][1], acc[3][1], 0, 0, 0);
    }
}

__global__ __launch_bounds__(512, 4)
void critic_kernel(const float* __restrict__ lat,
                   const bf16* __restrict__ p0, const float* __restrict__ b0,
                   const bf16* __restrict__ p1, const float* __restrict__ b1,
                   const bf16* __restrict__ p2, const float* __restrict__ b2,
                   const bf16* __restrict__ hw1b, const float* __restrict__ hb1,
                   const float* __restrict__ hw2, const float* __restrict__ hb2,
                   float* __restrict__ scores_tmp) {
    __shared__ __align__(16) char smem[SMEM_BYTES];
    bf16  (*xT)[XT_LD]  = (bf16(*)[XT_LD])smem;
    bf16  (*a1T)[A_LD]  = (bf16(*)[A_LD])smem;            // overlays xT after conv0
    bf16  (*a2T)[A_LD]  = (bf16(*)[A_LD])(smem + OFF_A2); // ditto
    float* feat = (float*)(smem + OFF_FEAT);
    float* hbuf = (float*)(smem + OFF_H);

    const int tid = threadIdx.x;
    const int bx  = blockIdx.x;
    const int b   = bx / (NW / 4);
    const int wi  = bx % (NW / 4);
    const int w0  = 4 * wi;

    // ---- stage 4 adjacent windows: 100*256 floats = 6400 float4 ----
    {
        const float4* src4 = (const float4*)(lat + ((size_t)b * T_LEN + (size_t)w0 * WS) * D0);
        #pragma unroll
        for (int it = 0; it < 13; ++it) {
            int g = tid + it * 512;
            if (g < 6400) {
                int l = g >> 6, c0 = (g & 63) * 4;
                int win = l / 25, lr = l - win * 25;
                int r = 31 * win + lr + 3;
                float4 v = src4[g];
                bf16x4 o = {(bf16)v.x, (bf16)v.y, (bf16)v.z, (bf16)v.w};
                *(bf16x4*)&xT[r][c0] = o;
            }
        }
        // zero xT pad rows 31j+{0,1,2,28,29,30}, j=0..3: 24 rows x 64 bf16x4
        bf16x4 z4 = {};
        #pragma unroll
        for (int it = 0; it < 3; ++it) {
            int i = tid + it * 512;
            int rr = i >> 6, c0 = (i & 63) * 4;
            int j = rr / 6, t6 = rr - 6 * j;
            int r = 31 * j + ((t6 < 3) ? t6 : t6 + 25);
            *(bf16x4*)&xT[r][c0] = z4;
        }
    }
    // NOTE: no __syncthreads here — conv_phase issues its A prefetch first,
    // then barriers internally.

    const int lane = tid & 63, wv = tid >> 6;
    const int win = wv & 3, mtg = wv >> 2;        // wave = (window, co-half)
    const int m = lane & 15, q = lane >> 4;
    const bf16* xb  = &xT[m][q * 8];
    const bf16* a1b = &a1T[m][q * 8];

    // ================= conv0: Cin=256 (8 K-steps), K=7, pad=3 =================
    f32x4 acc[4][2] = {};
    conv_phase<56, 8, XT_LD>((const bf16x8*)p0 + (size_t)mtg * 256 + lane,
                             xb, 31 * win, acc);
    __syncthreads();   // xT dead; region reused for a1T/a2T
    // zero a1T+a2T pad rows 29j+{0,1,27,28}: 16 rows x 32 bf16x4 each
    {
        bf16x4 z4 = {};
        #pragma unroll
        for (int it = 0; it < 2; ++it) {
            int i = tid + it * 512;
            int arr = i >> 9, rr = (i >> 5) & 15, c0 = (i & 31) * 4;
            int j = rr >> 2, t4 = rr & 3;
            int r = 29 * j + ((t4 < 2) ? t4 : t4 + 25);
            if (arr == 0) *(bf16x4*)&a1T[r][c0] = z4;
            else          *(bf16x4*)&a2T[r][c0] = z4;
        }
    }
    // conv0 epilogue: gelu -> a1T  (C/D: col=nt*16+m, row=q*4+r within tile)
    #pragma unroll
    for (int i = 0; i < 4; ++i) {
        int co0 = (mtg * 4 + i) * 16 + q * 4;
        f32x4 bv = *(const f32x4*)&b0[co0];
        #pragma unroll
        for (int nt = 0; nt < 2; ++nt) {
            int l = nt * 16 + m;
            if (l < 25) {
                bf16x4 v;
                #pragma unroll
                for (int r = 0; r < 4; ++r)
                    v[r] = (bf16)gelu_fast(acc[i][nt][r] + bv[r]);
                *(bf16x4*)&a1T[l + 2 + 29 * win][co0] = v;
            }
        }
    }
    // (barrier inside conv_phase)

    // ================= conv1: Cin=128 (4 K-steps), K=5, pad=2 =================
    f32x4 c1[4][2] = {};
    conv_phase<20, 4, A_LD>((const bf16x8*)p1 + (size_t)mtg * 256 + lane,
                            a1b, 29 * win, c1);
    // epilogue -> a2T (valid conv1 reads stay below a2T; garbage discarded)
    #pragma unroll
    for (int i = 0; i < 4; ++i) {
        int co0 = (mtg * 4 + i) * 16 + q * 4;
        f32x4 bv = *(const f32x4*)&b1[co0];
        #pragma unroll
        for (int nt = 0; nt < 2; ++nt) {
            int l = nt * 16 + m;
            if (l < 25) {
                bf16x4 v;
                #pragma unroll
                for (int r = 0; r < 4; ++r)
                    v[r] = (bf16)gelu_fast(c1[i][nt][r] + bv[r]);
                *(bf16x4*)&a2T[l + 2 + 29 * win][co0] = v;
            }
        }
    }
    // (barrier inside conv_phase)

    // ================= conv2: Cin=128 (4 K-steps), K=5, pad=2 =================
    f32x4 c2[4][2] = {};
    conv_phase<20, 4, A_LD>((const bf16x8*)p2 + (size_t)mtg * 256 + lane,
                            &a2T[m][q * 8], 29 * win, c2);
    // ===== register pooling: gelu + shuffle-reduce over l (lane bits 0-3) =====
    #pragma unroll
    for (int i = 0; i < 4; ++i) {
        int co0 = (mtg * 4 + i) * 16 + q * 4;
        f32x4 bv = *(const f32x4*)&b2[co0];
        f32x4 pool;
        #pragma unroll
        for (int r = 0; r < 4; ++r) {
            float s  = gelu_fast(c2[i][0][r] + bv[r]);       // l = m < 25
            float g1 = gelu_fast(c2[i][1][r] + bv[r]);       // l = 16+m
            s += (m < 9) ? g1 : 0.0f;
            s += __shfl_xor(s, 1);
            s += __shfl_xor(s, 2);
            s += __shfl_xor(s, 4);
            s += __shfl_xor(s, 8);
            pool[r] = s * 0.04f;
        }
        if (m == 0) *(f32x4*)&feat[win * 128 + co0] = pool;
    }
    __syncthreads();

    // ===== head: 512 dots of length 128; one per thread =====
    {
        int wb = tid >> 7, co = tid & 127;
        const bf16x8* row = (const bf16x8*)(hw1b + co * H);
        const float* f0 = feat + wb * 128;
        float a0h = hb1[co];
        #pragma unroll
        for (int jv = 0; jv < 16; ++jv) {
            bf16x8 w8 = row[jv];
            #pragma unroll
            for (int u = 0; u < 8; ++u)
                a0h += (float)w8[u] * f0[jv * 8 + u];
        }
        hbuf[wb * 128 + co] = gelu_fast(a0h);
    }
    __syncthreads();

    if (tid < 256) {
        int win2 = tid >> 6, j = tid & 63;    // 4 waves -> 4 windows
        const float* hb = hbuf + win2 * 128;
        float p = hw2[j] * hb[j] + hw2[j + 64] * hb[j + 64];
        #pragma unroll
        for (int off = 32; off > 0; off >>= 1) p += __shfl_down(p, off);
        if (j == 0) {
            float z = p + hb2[0];
            scores_tmp[b * NW + w0 + win2] = 5.0f / (1.0f + expf(-z));
        }
    }
}

// ---------------------------------------------------------------------------
__global__ void finalize_kernel(const float* __restrict__ tmp, float* __restrict__ out) {
    int w = blockIdx.x * 256 + threadIdx.x;
    if (w < NW) {
        float s = 0.0f;
        #pragma unroll
        for (int b = 0; b < BATCH; ++b) s += tmp[b * NW + w];
        s *= 0.125f;
        out[w] = s;
        out[NW + w] = (s < 3.5f) ? 1.0f : 0.0f;
    }
}

// ---------------------------------------------------------------------------
extern "C" void kernel_launch(void* const* d_in, const int* in_sizes, int n_in,
                              void* d_out, int out_size, void* d_ws, size_t ws_size,
                              hipStream_t stream) {
    const float* lat  = (const float*)d_in[0];
    const float* c0w  = (const float*)d_in[1];
    const float* c0b  = (const float*)d_in[2];
    const float* c1w  = (const float*)d_in[3];
    const float* c1b  = (const float*)d_in[4];
    const float* c2w  = (const float*)d_in[5];
    const float* c2b  = (const float*)d_in[6];
    const float* hw1  = (const float*)d_in[7];
    const float* hb1  = (const float*)d_in[8];
    const float* hw2  = (const float*)d_in[9];
    const float* hb2  = (const float*)d_in[10];

    // workspace layout
    bf16* p0   = (bf16*)d_ws;                                 // 458752 B
    bf16* p1   = (bf16*)((char*)d_ws + 458752);               // 163840 B
    bf16* p2   = (bf16*)((char*)d_ws + 622592);               // 163840 B
    bf16* hw1b = (bf16*)((char*)d_ws + 786432);               //  32768 B
    float* tmp = (float*)((char*)d_ws + 819200);              //  32000 B

    prep_kernel<<<1600, 256, 0, stream>>>(c0w, c1w, c2w, hw1, p0, p1, p2, hw1b);
    critic_kernel<<<BATCH * (NW / 4), 512, 0, stream>>>(lat, p0, c0b, p1, c1b, p2, c2b,
                                                        hw1b, hb1, hw2, hb2, tmp);
    finalize_kernel<<<4, 256, 0, stream>>>(tmp, (float*)d_out);
}

// Round 4
// 498.417 us; speedup vs baseline: 1.0565x; 1.0252x over previous
//
#include <hip/hip_runtime.h>
#include <math.h>

// Problem constants (match setup_inputs)
#define BATCH 8
#define T_LEN 25000
#define NW    1000
#define WS    25
#define D0    256
#define H     128

typedef __bf16 bf16;
typedef bf16 bf16x8 __attribute__((ext_vector_type(8)));
typedef bf16 bf16x4 __attribute__((ext_vector_type(4)));
typedef float f32x4 __attribute__((ext_vector_type(4)));

// tanh-form GELU via v_exp_f32. |err| <= ~3e-3 absolute.
__device__ __forceinline__ float gelu_fast(float x) {
    float y = 0.7978845608f * x * (1.0f + 0.044715f * x * x);
    float e = __expf(2.0f * y);
    float t = 1.0f - 2.0f * __builtin_amdgcn_rcpf(e + 1.0f);
    return 0.5f * x * (1.0f + t);
}

// ---------------------------------------------------------------------------
// Weight repack (16x16x32 A-fragments, R3-verified):
//   dst[ ((k*KSn + ks)*8 + mt)*512 + lane*8 + j ]
//     = w[ co=mt*16+(lane&15) ][ ci=ks*32+(lane>>4)*8+j ][ k ]
// ---------------------------------------------------------------------------
__device__ __forceinline__ void repack_one(const float* __restrict__ w,
                                           bf16* __restrict__ dst, int idx,
                                           int Cin, int K, int KSn) {
    int j    = idx & 7;
    int lane = (idx >> 3) & 63;
    int mt   = (idx >> 9) & 7;
    int ks   = (idx >> 12) % KSn;
    int k    = idx / (4096 * KSn);
    int co = mt * 16 + (lane & 15);
    int ci = ks * 32 + (lane >> 4) * 8 + j;
    dst[idx] = (bf16)w[(co * Cin + ci) * K + k];
}

__global__ void prep_kernel(const float* __restrict__ c0w, const float* __restrict__ c1w,
                            const float* __restrict__ c2w, const float* __restrict__ hw1,
                            bf16* __restrict__ p0, bf16* __restrict__ p1,
                            bf16* __restrict__ p2, bf16* __restrict__ hw1b) {
    int t = blockIdx.x * 256 + threadIdx.x;
    if (t < 229376) {
        repack_one(c0w, p0, t, 256, 7, 8);
    } else if (t < 311296) {
        repack_one(c1w, p1, t - 229376, 128, 5, 4);
    } else if (t < 393216) {
        repack_one(c2w, p2, t - 311296, 128, 5, 4);
    } else if (t < 409600) {
        int i = t - 393216;
        hw1b[i] = (bf16)hw1[i];
    }
}

// ---------------------------------------------------------------------------
// Fused critic, W=4 windows/block, 512 threads = 8 waves.
// Wave partition: wv -> (win = wv&3, mtg = wv>>2); each wave 4 m-tiles x 1 win.
//
// R4 = R3 + EARLY-CLOBBER FIX. R3's ISSUE_A used "=v" outputs in a
// multi-instruction asm block sharing an address operand: LLVM may allocate an
// output quad over the address pair (outputs assumed written after all inputs
// read -> false for 4 sequential loads) -> loads 1-3 from clobbered address ->
// device abort. "=&v" forces disjoint allocation.
//
// Theory under test (from R2: VGPR=64 proved compiler folded the source-level
// pipeline): per-step L2 A-delivery serializes with MFMA; forcing a depth-2
// asm pipeline with counted vmcnt (T3/T4 at register level) overlaps them.
// Safety (rule #18): waitcnt asm ties waited regs as "+v" AND is followed by
// sched_barrier(0). Compiler-inserted vmem ops between our groups only make
// the counted wait stricter (group s is always among the oldest retired).
//
// LDS (74848 B -> 2 blocks/CU): layout + bounds audit unchanged (R3-verified):
// xT[134][264]@0 (70752 B), a1T[123][136]@0 overlay, a2T@33456, feat@70752,
// hbuf@72800.
// __launch_bounds__(512,4): 128-reg cap (VGPR cliff at 128 -> 1 block/CU).
// Pipeline regs: a[3][4]=48 + bb[2][2]=16 + acc=32 + addr ~= 116.
// ---------------------------------------------------------------------------
#define XT_LD 264
#define A_LD  136
#define OFF_A2   33456
#define OFF_FEAT 70752
#define OFF_H    72800
#define SMEM_BYTES 74848

// Issue one step-group: 4 x global_load_dwordx4 at base + {0,1K,2K,3K}.
// "=&v" early-clobber: outputs must not alias the address pair (%4) — the
// block executes 4 loads sequentially and each must see an intact address.
#define ISSUE_A(buf, base) \
    asm volatile("global_load_dwordx4 %0, %4, off\n\t"              \
                 "global_load_dwordx4 %1, %4, off offset:1024\n\t"  \
                 "global_load_dwordx4 %2, %4, off offset:2048\n\t"  \
                 "global_load_dwordx4 %3, %4, off offset:3072"      \
                 : "=&v"((buf)[0]), "=&v"((buf)[1]), "=&v"((buf)[2]), "=&v"((buf)[3]) \
                 : "v"(base))

// Counted wait finalizing step-s group. "+v" ties make every consumer of the
// group data-depend on this asm (cannot hoist above); rule #18 fence after.
#define WAIT_A(buf, Nlit) do {                                       \
    asm volatile("s_waitcnt vmcnt(" #Nlit ")"                        \
                 : "+v"((buf)[0]), "+v"((buf)[1]), "+v"((buf)[2]), "+v"((buf)[3])); \
    __builtin_amdgcn_sched_barrier(0);                               \
} while (0)

// Producer-side barrier: drain own LDS writes, raw s_barrier (no vmcnt drain
// -> A prefetch issued before this stays in flight across it).
__device__ __forceinline__ void lds_barrier() {
    asm volatile("s_waitcnt lgkmcnt(0)" ::: "memory");
    __builtin_amdgcn_s_barrier();
}

// Software-pipelined conv phase. A: global (L2-resident weights), asm loads,
// depth-2 (8-12 loads in flight, vmcnt(8) steady state). B: LDS, depth-1,
// left to the compiler's lgkmcnt management. Performs the phase-entry barrier
// internally (after issuing the first two A groups).
template<int NS, int KSN, int LD>
__device__ __forceinline__ void conv_phase_pipe(const char* __restrict__ Abase,
                                                const bf16* __restrict__ bbase,
                                                int rowoff, f32x4 (&acc)[4][2]) {
    bf16x8 a[3][4];
    bf16x8 bb[2][2];
    ISSUE_A(a[0], Abase);
    ISSUE_A(a[1], Abase + 8192);
    lds_barrier();
    {
        const bf16* pB = bbase + rowoff * LD;           // s=0: k=0, ks=0
        bb[0][0] = *(const bf16x8*)pB;
        bb[0][1] = *(const bf16x8*)(pB + 16 * LD);
    }
    #pragma unroll
    for (int s = 0; s < NS; ++s) {
        const int cur = s & 1, nxt = cur ^ 1;
        const int ap = s % 3;
        if (s + 2 < NS)
            ISSUE_A(a[(s + 2) % 3], Abase + (size_t)(s + 2) * 8192);
        // outstanding after issue: groups s,s+1,s+2 = 12 loads -> vmcnt(8)
        // completes group s. Tails: 8->vmcnt(4), 4->vmcnt(0).
        if (s + 2 < NS)      WAIT_A(a[ap], 8);
        else if (s + 1 < NS) WAIT_A(a[ap], 4);
        else                 WAIT_A(a[ap], 0);
        if (s + 1 < NS) {                                // B prefetch, dist 1
            const int k1 = (s + 1) / KSN, ks1 = (s + 1) % KSN;
            const bf16* pB = bbase + (k1 + rowoff) * LD + ks1 * 32;
            bb[nxt][0] = *(const bf16x8*)pB;
            bb[nxt][1] = *(const bf16x8*)(pB + 16 * LD);
        }
        acc[0][0] = __builtin_amdgcn_mfma_f32_16x16x32_bf16(a[ap][0], bb[cur][0], acc[0][0], 0, 0, 0);
        acc[0][1] = __builtin_amdgcn_mfma_f32_16x16x32_bf16(a[ap][0], bb[cur][1], acc[0][1], 0, 0, 0);
        acc[1][0] = __builtin_amdgcn_mfma_f32_16x16x32_bf16(a[ap][1], bb[cur][0], acc[1][0], 0, 0, 0);
        acc[1][1] = __builtin_amdgcn_mfma_f32_16x16x32_bf16(a[ap][1], bb[cur][1], acc[1][1], 0, 0, 0);
        acc[2][0] = __builtin_amdgcn_mfma_f32_16x16x32_bf16(a[ap][2], bb[cur][0], acc[2][0], 0, 0, 0);
        acc[2][1] = __builtin_amdgcn_mfma_f32_16x16x32_bf16(a[ap][2], bb[cur][1], acc[2][1], 0, 0, 0);
        acc[3][0] = __builtin_amdgcn_mfma_f32_16x16x32_bf16(a[ap][3], bb[cur][0], acc[3][0], 0, 0, 0);
        acc[3][1] = __builtin_amdgcn_mfma_f32_16x16x32_bf16(a[ap][3], bb[cur][1], acc[3][1], 0, 0, 0);
    }
}

__global__ __launch_bounds__(512, 4)
void critic_kernel(const float* __restrict__ lat,
                   const bf16* __restrict__ p0, const float* __restrict__ b0,
                   const bf16* __restrict__ p1, const float* __restrict__ b1,
                   const bf16* __restrict__ p2, const float* __restrict__ b2,
                   const bf16* __restrict__ hw1b, const float* __restrict__ hb1,
                   const float* __restrict__ hw2, const float* __restrict__ hb2,
                   float* __restrict__ scores_tmp) {
    __shared__ __align__(16) char smem[SMEM_BYTES];
    bf16  (*xT)[XT_LD]  = (bf16(*)[XT_LD])smem;
    bf16  (*a1T)[A_LD]  = (bf16(*)[A_LD])smem;            // overlays xT after conv0
    bf16  (*a2T)[A_LD]  = (bf16(*)[A_LD])(smem + OFF_A2); // ditto
    float* feat = (float*)(smem + OFF_FEAT);
    float* hbuf = (float*)(smem + OFF_H);

    const int tid = threadIdx.x;
    const int bx  = blockIdx.x;
    const int b   = bx / (NW / 4);
    const int wi  = bx % (NW / 4);
    const int w0  = 4 * wi;

    // ---- stage 4 adjacent windows: 100*256 floats = 6400 float4 ----
    {
        const float4* src4 = (const float4*)(lat + ((size_t)b * T_LEN + (size_t)w0 * WS) * D0);
        #pragma unroll
        for (int it = 0; it < 13; ++it) {
            int g = tid + it * 512;
            if (g < 6400) {
                int l = g >> 6, c0 = (g & 63) * 4;
                int win = l / 25, lr = l - win * 25;
                int r = 31 * win + lr + 3;
                float4 v = src4[g];
                bf16x4 o = {(bf16)v.x, (bf16)v.y, (bf16)v.z, (bf16)v.w};
                *(bf16x4*)&xT[r][c0] = o;
            }
        }
        // zero xT pad rows 31j+{0,1,2,28,29,30}, j=0..3: 24 rows x 64 bf16x4
        bf16x4 z4 = {};
        #pragma unroll
        for (int it = 0; it < 3; ++it) {
            int i = tid + it * 512;
            int rr = i >> 6, c0 = (i & 63) * 4;
            int j = rr / 6, t6 = rr - 6 * j;
            int r = 31 * j + ((t6 < 3) ? t6 : t6 + 25);
            *(bf16x4*)&xT[r][c0] = z4;
        }
    }
    // NOTE: no __syncthreads here — conv_phase_pipe issues A prefetch first,
    // then does lgkmcnt(0) + raw s_barrier internally.

    const int lane = tid & 63, wv = tid >> 6;
    const int win = wv & 3, mtg = wv >> 2;        // wave = (window, co-half)
    const int m = lane & 15, q = lane >> 4;
    const bf16* xb  = &xT[m][q * 8];
    const bf16* a1b = &a1T[m][q * 8];
    const char* A0 = (const char*)p0 + (size_t)(mtg * 256 + lane) * 16;
    const char* A1 = (const char*)p1 + (size_t)(mtg * 256 + lane) * 16;
    const char* A2 = (const char*)p2 + (size_t)(mtg * 256 + lane) * 16;

    // ================= conv0: Cin=256 (8 K-steps), K=7, pad=3 =================
    f32x4 acc[4][2] = {};
    conv_phase_pipe<56, 8, XT_LD>(A0, xb, 31 * win, acc);
    __syncthreads();   // xT dead; region reused for a1T/a2T (vmcnt=0 already)
    // zero a1T+a2T pad rows 29j+{0,1,27,28}: 16 rows x 32 bf16x4 each
    {
        bf16x4 z4 = {};
        #pragma unroll
        for (int it = 0; it < 2; ++it) {
            int i = tid + it * 512;
            int arr = i >> 9, rr = (i >> 5) & 15, c0 = (i & 31) * 4;
            int j = rr >> 2, t4 = rr & 3;
            int r = 29 * j + ((t4 < 2) ? t4 : t4 + 25);
            if (arr == 0) *(bf16x4*)&a1T[r][c0] = z4;
            else          *(bf16x4*)&a2T[r][c0] = z4;
        }
    }
    // conv0 epilogue: gelu -> a1T  (C/D: col=nt*16+m, row=q*4+r within tile)
    #pragma unroll
    for (int i = 0; i < 4; ++i) {
        int co0 = (mtg * 4 + i) * 16 + q * 4;
        f32x4 bv = *(const f32x4*)&b0[co0];
        #pragma unroll
        for (int nt = 0; nt < 2; ++nt) {
            int l = nt * 16 + m;
            if (l < 25) {
                bf16x4 v;
                #pragma unroll
                for (int r = 0; r < 4; ++r)
                    v[r] = (bf16)gelu_fast(acc[i][nt][r] + bv[r]);
                *(bf16x4*)&a1T[l + 2 + 29 * win][co0] = v;
            }
        }
    }
    // (barrier inside conv_phase_pipe)

    // ================= conv1: Cin=128 (4 K-steps), K=5, pad=2 =================
    f32x4 c1[4][2] = {};
    conv_phase_pipe<20, 4, A_LD>(A1, a1b, 29 * win, c1);
    // epilogue -> a2T (valid conv1 reads stay below a2T; garbage discarded)
    #pragma unroll
    for (int i = 0; i < 4; ++i) {
        int co0 = (mtg * 4 + i) * 16 + q * 4;
        f32x4 bv = *(const f32x4*)&b1[co0];
        #pragma unroll
        for (int nt = 0; nt < 2; ++nt) {
            int l = nt * 16 + m;
            if (l < 25) {
                bf16x4 v;
                #pragma unroll
                for (int r = 0; r < 4; ++r)
                    v[r] = (bf16)gelu_fast(c1[i][nt][r] + bv[r]);
                *(bf16x4*)&a2T[l + 2 + 29 * win][co0] = v;
            }
        }
    }
    // (barrier inside conv_phase_pipe)

    // ================= conv2: Cin=128 (4 K-steps), K=5, pad=2 =================
    f32x4 c2[4][2] = {};
    conv_phase_pipe<20, 4, A_LD>(A2, &a2T[m][q * 8], 29 * win, c2);
    // ===== register pooling: gelu + shuffle-reduce over l (lane bits 0-3) =====
    #pragma unroll
    for (int i = 0; i < 4; ++i) {
        int co0 = (mtg * 4 + i) * 16 + q * 4;
        f32x4 bv = *(const f32x4*)&b2[co0];
        f32x4 pool;
        #pragma unroll
        for (int r = 0; r < 4; ++r) {
            float s  = gelu_fast(c2[i][0][r] + bv[r]);       // l = m < 25
            float g1 = gelu_fast(c2[i][1][r] + bv[r]);       // l = 16+m
            s += (m < 9) ? g1 : 0.0f;
            s += __shfl_xor(s, 1);
            s += __shfl_xor(s, 2);
            s += __shfl_xor(s, 4);
            s += __shfl_xor(s, 8);
            pool[r] = s * 0.04f;
        }
        if (m == 0) *(f32x4*)&feat[win * 128 + co0] = pool;
    }
    __syncthreads();

    // ===== head: 512 dots of length 128; one per thread =====
    {
        int wb = tid >> 7, co = tid & 127;
        const bf16x8* row = (const bf16x8*)(hw1b + co * H);
        const float* f0 = feat + wb * 128;
        float a0h = hb1[co];
        #pragma unroll
        for (int jv = 0; jv < 16; ++jv) {
            bf16x8 w8 = row[jv];
            #pragma unroll
            for (int u = 0; u < 8; ++u)
                a0h += (float)w8[u] * f0[jv * 8 + u];
        }
        hbuf[wb * 128 + co] = gelu_fast(a0h);
    }
    __syncthreads();

    if (tid < 256) {
        int win2 = tid >> 6, j = tid & 63;    // 4 waves -> 4 windows
        const float* hb = hbuf + win2 * 128;
        float p = hw2[j] * hb[j] + hw2[j + 64] * hb[j + 64];
        #pragma unroll
        for (int off = 32; off > 0; off >>= 1) p += __shfl_down(p, off);
        if (j == 0) {
            float z = p + hb2[0];
            scores_tmp[b * NW + w0 + win2] = 5.0f / (1.0f + expf(-z));
        }
    }
}

// ---------------------------------------------------------------------------
__global__ void finalize_kernel(const float* __restrict__ tmp, float* __restrict__ out) {
    int w = blockIdx.x * 256 + threadIdx.x;
    if (w < NW) {
        float s = 0.0f;
        #pragma unroll
        for (int b = 0; b < BATCH; ++b) s += tmp[b * NW + w];
        s *= 0.125f;
        out[w] = s;
        out[NW + w] = (s < 3.5f) ? 1.0f : 0.0f;
    }
}

// ---------------------------------------------------------------------------
extern "C" void kernel_launch(void* const* d_in, const int* in_sizes, int n_in,
                              void* d_out, int out_size, void* d_ws, size_t ws_size,
                              hipStream_t stream) {
    const float* lat  = (const float*)d_in[0];
    const float* c0w  = (const float*)d_in[1];
    const float* c0b  = (const float*)d_in[2];
    const float* c1w  = (const float*)d_in[3];
    const float* c1b  = (const float*)d_in[4];
    const float* c2w  = (const float*)d_in[5];
    const float* c2b  = (const float*)d_in[6];
    const float* hw1  = (const float*)d_in[7];
    const float* hb1  = (const float*)d_in[8];
    const float* hw2  = (const float*)d_in[9];
    const float* hb2  = (const float*)d_in[10];

    // workspace layout
    bf16* p0   = (bf16*)d_ws;                                 // 458752 B
    bf16* p1   = (bf16*)((char*)d_ws + 458752);               // 163840 B
    bf16* p2   = (bf16*)((char*)d_ws + 622592);               // 163840 B
    bf16* hw1b = (bf16*)((char*)d_ws + 786432);               //  32768 B
    float* tmp = (float*)((char*)d_ws + 819200);              //  32000 B

    prep_kernel<<<1600, 256, 0, stream>>>(c0w, c1w, c2w, hw1, p0, p1, p2, hw1b);
    critic_kernel<<<BATCH * (NW / 4), 512, 0, stream>>>(lat, p0, c0b, p1, c1b, p2, c2b,
                                                        hw1b, hb1, hw2, hb2, tmp);
    finalize_kernel<<<4, 256, 0, stream>>>(tmp, (float*)d_out);
}

// Round 6
// 437.482 us; speedup vs baseline: 1.2037x; 1.1393x over previous
//
#include <hip/hip_runtime.h>
#include <math.h>

// Problem constants (match setup_inputs)
#define BATCH 8
#define T_LEN 25000
#define NW    1000
#define WS    25
#define D0    256
#define H     128

typedef __bf16 bf16;
typedef bf16 bf16x8 __attribute__((ext_vector_type(8)));
typedef bf16 bf16x4 __attribute__((ext_vector_type(4)));
typedef float f32x4 __attribute__((ext_vector_type(4)));

// tanh-form GELU via v_exp_f32. |err| <= ~3e-3 absolute.
__device__ __forceinline__ float gelu_fast(float x) {
    float y = 0.7978845608f * x * (1.0f + 0.044715f * x * x);
    float e = __expf(2.0f * y);
    float t = 1.0f - 2.0f * __builtin_amdgcn_rcpf(e + 1.0f);
    return 0.5f * x * (1.0f + t);
}

// ---------------------------------------------------------------------------
// Weight repack (16x16x32 A-fragments, R3-verified):
//   dst[ ((k*KSn + ks)*8 + mt)*512 + lane*8 + j ]
//     = w[ co=mt*16+(lane&15) ][ ci=ks*32+(lane>>4)*8+j ][ k ]
// ---------------------------------------------------------------------------
__device__ __forceinline__ void repack_one(const float* __restrict__ w,
                                           bf16* __restrict__ dst, int idx,
                                           int Cin, int K, int KSn) {
    int j    = idx & 7;
    int lane = (idx >> 3) & 63;
    int mt   = (idx >> 9) & 7;
    int ks   = (idx >> 12) % KSn;
    int k    = idx / (4096 * KSn);
    int co = mt * 16 + (lane & 15);
    int ci = ks * 32 + (lane >> 4) * 8 + j;
    dst[idx] = (bf16)w[(co * Cin + ci) * K + k];
}

__global__ void prep_kernel(const float* __restrict__ c0w, const float* __restrict__ c1w,
                            const float* __restrict__ c2w, const float* __restrict__ hw1,
                            bf16* __restrict__ p0, bf16* __restrict__ p1,
                            bf16* __restrict__ p2, bf16* __restrict__ hw1b) {
    int t = blockIdx.x * 256 + threadIdx.x;
    if (t < 229376) {
        repack_one(c0w, p0, t, 256, 7, 8);
    } else if (t < 311296) {
        repack_one(c1w, p1, t - 229376, 128, 5, 4);
    } else if (t < 393216) {
        repack_one(c2w, p2, t - 311296, 128, 5, 4);
    } else if (t < 409600) {
        int i = t - 393216;
        hw1b[i] = (bf16)hw1[i];
    }
}

// ---------------------------------------------------------------------------
// Fused critic, W=4 windows/block, 256 threads = 4 waves.
//
// R5 partition (TA/LDS balance fix): wave wv -> (wp = wv&1 window-pair,
// mtg = wv>>1 co-half). Per (k,ks) step each wave does 4 A-loads (its 4
// m-tiles) + 4 B ds_reads (2 windows x 2 nt) -> 16 MFMAs. Rationale: R1-R4's
// wave=(win,mtg) shape fed only 2 MFMAs per A-load -> TA port demand 6144
// wave-loads x 16cyc = ~98K cyc/CU-round, the top pipe (> matrix 60K).
// R0's shape was the mirror (B dup x4 -> LDS ~100K). A=4xB=4 puts TA ~48K,
// LDS ~50K, VALU ~49K, matrix 60K = top pipe for the first time.
//
// A-side asm pipeline (R4-verified): repack layout gives mtg's 4 m-tiles at
// byte offsets {0,1K,2K,3K} from Abase = p + mtg*4096 + lane*16, step stride
// 8192 -> ISSUE_A/WAIT_A identical to R4. B: depth-1 prefetch, bb[2][4].
//
// LDS (74848 B -> 2 blocks/CU): layout + bounds audit unchanged (R3-verified):
// xT[134][264]@0 (70752 B), a1T[123][136]@0 overlay, a2T@33456, feat@70752,
// hbuf@72800. conv0 max read 130*528+512=69152<70752; conv1 <=33424<33456.
// __launch_bounds__(256,2): 256-reg budget. Regs: a 48 + bb 32 + acc 64 +
// addr/misc ~30 = ~175 < 256, no spill; 2 blocks/CU (LDS-bound), 2 waves/SIMD.
// ---------------------------------------------------------------------------
#define XT_LD 264
#define A_LD  136
#define OFF_A2   33456
#define OFF_FEAT 70752
#define OFF_H    72800
#define SMEM_BYTES 74848

// Issue one step-group: 4 x global_load_dwordx4 at base + {0,1K,2K,3K}.
// "=&v" early-clobber (R4 fix): outputs must not alias the address pair.
#define ISSUE_A(buf, base) \
    asm volatile("global_load_dwordx4 %0, %4, off\n\t"              \
                 "global_load_dwordx4 %1, %4, off offset:1024\n\t"  \
                 "global_load_dwordx4 %2, %4, off offset:2048\n\t"  \
                 "global_load_dwordx4 %3, %4, off offset:3072"      \
                 : "=&v"((buf)[0]), "=&v"((buf)[1]), "=&v"((buf)[2]), "=&v"((buf)[3]) \
                 : "v"(base))

// Counted wait finalizing step-s group. "+v" ties make every consumer of the
// group data-depend on this asm (cannot hoist above); rule #18 fence after.
#define WAIT_A(buf, Nlit) do {                                       \
    asm volatile("s_waitcnt vmcnt(" #Nlit ")"                        \
                 : "+v"((buf)[0]), "+v"((buf)[1]), "+v"((buf)[2]), "+v"((buf)[3])); \
    __builtin_amdgcn_sched_barrier(0);                               \
} while (0)

// Producer-side barrier: drain own LDS writes, raw s_barrier (no vmcnt drain
// -> A prefetch issued before this stays in flight across it).
__device__ __forceinline__ void lds_barrier() {
    asm volatile("s_waitcnt lgkmcnt(0)" ::: "memory");
    __builtin_amdgcn_s_barrier();
}

// Software-pipelined conv phase. A: global (L2-resident weights), asm loads,
// depth-2 (8-12 loads in flight, vmcnt(8) steady state). B: LDS, depth-1
// (bb[2][4]: 2 windows x 2 nt), compiler-managed lgkmcnt. Performs the
// phase-entry barrier internally (after issuing the first two A groups).
// r0/r1 = LDS row offsets of the wave's two windows.
template<int NS, int KSN, int LD>
__device__ __forceinline__ void conv_phase_pipe(const char* __restrict__ Abase,
                                                const bf16* __restrict__ bbase,
                                                int r0, int r1, f32x4 (&acc)[4][4]) {
    bf16x8 a[3][4];
    bf16x8 bb[2][4];
    ISSUE_A(a[0], Abase);
    ISSUE_A(a[1], Abase + 8192);
    lds_barrier();
    {
        const bf16* pB0 = bbase + r0 * LD;              // s=0: k=0, ks=0
        const bf16* pB1 = bbase + r1 * LD;
        bb[0][0] = *(const bf16x8*)(pB0);
        bb[0][1] = *(const bf16x8*)(pB0 + 16 * LD);
        bb[0][2] = *(const bf16x8*)(pB1);
        bb[0][3] = *(const bf16x8*)(pB1 + 16 * LD);
    }
    #pragma unroll
    for (int s = 0; s < NS; ++s) {
        const int cur = s & 1, nxt = cur ^ 1;
        const int ap = s % 3;
        if (s + 2 < NS)
            ISSUE_A(a[(s + 2) % 3], Abase + (size_t)(s + 2) * 8192);
        // outstanding after issue: groups s,s+1,s+2 = 12 loads -> vmcnt(8)
        // completes group s. Tails: 8->vmcnt(4), 4->vmcnt(0).
        if (s + 2 < NS)      WAIT_A(a[ap], 8);
        else if (s + 1 < NS) WAIT_A(a[ap], 4);
        else                 WAIT_A(a[ap], 0);
        if (s + 1 < NS) {                                // B prefetch, dist 1
            const int k1 = (s + 1) / KSN, ks1 = (s + 1) % KSN;
            const int o = k1 * LD + ks1 * 32;
            const bf16* pB0 = bbase + r0 * LD + o;
            const bf16* pB1 = bbase + r1 * LD + o;
            bb[nxt][0] = *(const bf16x8*)(pB0);
            bb[nxt][1] = *(const bf16x8*)(pB0 + 16 * LD);
            bb[nxt][2] = *(const bf16x8*)(pB1);
            bb[nxt][3] = *(const bf16x8*)(pB1 + 16 * LD);
        }
        #pragma unroll
        for (int i = 0; i < 4; ++i) {
            acc[i][0] = __builtin_amdgcn_mfma_f32_16x16x32_bf16(a[ap][i], bb[cur][0], acc[i][0], 0, 0, 0);
            acc[i][1] = __builtin_amdgcn_mfma_f32_16x16x32_bf16(a[ap][i], bb[cur][1], acc[i][1], 0, 0, 0);
            acc[i][2] = __builtin_amdgcn_mfma_f32_16x16x32_bf16(a[ap][i], bb[cur][2], acc[i][2], 0, 0, 0);
            acc[i][3] = __builtin_amdgcn_mfma_f32_16x16x32_bf16(a[ap][i], bb[cur][3], acc[i][3], 0, 0, 0);
        }
    }
}

__global__ __launch_bounds__(256, 2)
void critic_kernel(const float* __restrict__ lat,
                   const bf16* __restrict__ p0, const float* __restrict__ b0,
                   const bf16* __restrict__ p1, const float* __restrict__ b1,
                   const bf16* __restrict__ p2, const float* __restrict__ b2,
                   const bf16* __restrict__ hw1b, const float* __restrict__ hb1,
                   const float* __restrict__ hw2, const float* __restrict__ hb2,
                   float* __restrict__ scores_tmp) {
    __shared__ __align__(16) char smem[SMEM_BYTES];
    bf16  (*xT)[XT_LD]  = (bf16(*)[XT_LD])smem;
    bf16  (*a1T)[A_LD]  = (bf16(*)[A_LD])smem;            // overlays xT after conv0
    bf16  (*a2T)[A_LD]  = (bf16(*)[A_LD])(smem + OFF_A2); // ditto
    float* feat = (float*)(smem + OFF_FEAT);
    float* hbuf = (float*)(smem + OFF_H);

    const int tid = threadIdx.x;
    const int bx  = blockIdx.x;
    const int b   = bx / (NW / 4);
    const int wi  = bx % (NW / 4);
    const int w0  = 4 * wi;

    // ---- stage 4 adjacent windows: 100*256 floats = 6400 float4 ----
    {
        const float4* src4 = (const float4*)(lat + ((size_t)b * T_LEN + (size_t)w0 * WS) * D0);
        #pragma unroll
        for (int it = 0; it < 25; ++it) {
            int g = tid + it * 256;
            int l = g >> 6, c0 = (g & 63) * 4;
            int win = l / 25, lr = l - win * 25;
            int r = 31 * win + lr + 3;
            float4 v = src4[g];
            bf16x4 o = {(bf16)v.x, (bf16)v.y, (bf16)v.z, (bf16)v.w};
            *(bf16x4*)&xT[r][c0] = o;
        }
        // zero xT pad rows 31j+{0,1,2,28,29,30}, j=0..3: 24 rows x 64 bf16x4
        bf16x4 z4 = {};
        #pragma unroll
        for (int it = 0; it < 6; ++it) {
            int i = tid + it * 256;
            int rr = i >> 6, c0 = (i & 63) * 4;
            int j = rr / 6, t6 = rr - 6 * j;
            int r = 31 * j + ((t6 < 3) ? t6 : t6 + 25);
            *(bf16x4*)&xT[r][c0] = z4;
        }
    }
    // NOTE: no __syncthreads here — conv_phase_pipe issues A prefetch first,
    // then does lgkmcnt(0) + raw s_barrier internally.

    const int lane = tid & 63, wv = tid >> 6;
    const int wp = wv & 1, mtg = wv >> 1;       // wave = (window-pair, co-half)
    const int m = lane & 15, q = lane >> 4;
    const bf16* xb  = &xT[m][q * 8];
    const bf16* a1b = &a1T[m][q * 8];
    const char* A0 = (const char*)p0 + mtg * 4096 + lane * 16;
    const char* A1 = (const char*)p1 + mtg * 4096 + lane * 16;
    const char* A2 = (const char*)p2 + mtg * 4096 + lane * 16;

    // ================= conv0: Cin=256 (8 K-steps), K=7, pad=3 =================
    f32x4 acc[4][4] = {};
    conv_phase_pipe<56, 8, XT_LD>(A0, xb, 31 * (2 * wp), 31 * (2 * wp + 1), acc);
    __syncthreads();   // xT dead; region reused for a1T/a2T (vmcnt=0 already)
    // zero a1T+a2T pad rows 29j+{0,1,27,28}: 16 rows x 32 bf16x4 each
    {
        bf16x4 z4 = {};
        #pragma unroll
        for (int it = 0; it < 4; ++it) {
            int i = tid + it * 256;
            int arr = i >> 9, rr = (i >> 5) & 15, c0 = (i & 31) * 4;
            int j = rr >> 2, t4 = rr & 3;
            int r = 29 * j + ((t4 < 2) ? t4 : t4 + 25);
            if (arr == 0) *(bf16x4*)&a1T[r][c0] = z4;
            else          *(bf16x4*)&a2T[r][c0] = z4;
        }
    }
    // conv0 epilogue: gelu -> a1T  (C/D: col=nt*16+m, row=q*4+r within tile)
    #pragma unroll
    for (int i = 0; i < 4; ++i) {
        int co0 = (mtg * 4 + i) * 16 + q * 4;
        f32x4 bv = *(const f32x4*)&b0[co0];
        #pragma unroll
        for (int wq = 0; wq < 2; ++wq) {
            int win = 2 * wp + wq;
            #pragma unroll
            for (int nt = 0; nt < 2; ++nt) {
                int l = nt * 16 + m;
                if (l < 25) {
                    bf16x4 v;
                    #pragma unroll
                    for (int r = 0; r < 4; ++r)
                        v[r] = (bf16)gelu_fast(acc[i][2 * wq + nt][r] + bv[r]);
                    *(bf16x4*)&a1T[l + 2 + 29 * win][co0] = v;
                }
            }
        }
    }
    // (barrier inside conv_phase_pipe)

    // ================= conv1: Cin=128 (4 K-steps), K=5, pad=2 =================
    f32x4 c1[4][4] = {};
    conv_phase_pipe<20, 4, A_LD>(A1, a1b, 29 * (2 * wp), 29 * (2 * wp + 1), c1);
    // epilogue -> a2T (valid conv1 reads stay below a2T; garbage discarded)
    #pragma unroll
    for (int i = 0; i < 4; ++i) {
        int co0 = (mtg * 4 + i) * 16 + q * 4;
        f32x4 bv = *(const f32x4*)&b1[co0];
        #pragma unroll
        for (int wq = 0; wq < 2; ++wq) {
            int win = 2 * wp + wq;
            #pragma unroll
            for (int nt = 0; nt < 2; ++nt) {
                int l = nt * 16 + m;
                if (l < 25) {
                    bf16x4 v;
                    #pragma unroll
                    for (int r = 0; r < 4; ++r)
                        v[r] = (bf16)gelu_fast(c1[i][2 * wq + nt][r] + bv[r]);
                    *(bf16x4*)&a2T[l + 2 + 29 * win][co0] = v;
                }
            }
        }
    }
    // (barrier inside conv_phase_pipe)

    // ================= conv2: Cin=128 (4 K-steps), K=5, pad=2 =================
    f32x4 c2[4][4] = {};
    conv_phase_pipe<20, 4, A_LD>(A2, &a2T[m][q * 8], 29 * (2 * wp), 29 * (2 * wp + 1), c2);
    // ===== register pooling: gelu + shuffle-reduce over l (lane bits 0-3) =====
    #pragma unroll
    for (int i = 0; i < 4; ++i) {
        int co0 = (mtg * 4 + i) * 16 + q * 4;
        f32x4 bv = *(const f32x4*)&b2[co0];
        #pragma unroll
        for (int wq = 0; wq < 2; ++wq) {
            int win = 2 * wp + wq;
            f32x4 pool;
            #pragma unroll
            for (int r = 0; r < 4; ++r) {
                float s  = gelu_fast(c2[i][2 * wq][r] + bv[r]);       // l = m < 25
                float g1 = gelu_fast(c2[i][2 * wq + 1][r] + bv[r]);   // l = 16+m
                s += (m < 9) ? g1 : 0.0f;
                s += __shfl_xor(s, 1);
                s += __shfl_xor(s, 2);
                s += __shfl_xor(s, 4);
                s += __shfl_xor(s, 8);
                pool[r] = s * 0.04f;
            }
            if (m == 0) *(f32x4*)&feat[win * 128 + co0] = pool;
        }
    }
    __syncthreads();

    // ===== head: 512 dots of length 128; each thread does wins {wb, wb+2} =====
    {
        int wb = tid >> 7, co = tid & 127;
        const bf16x8* row = (const bf16x8*)(hw1b + co * H);
        const float* f0 = feat + wb * 128;
        const float* f1 = feat + (wb + 2) * 128;
        float a0h = hb1[co], a1h = a0h;
        #pragma unroll
        for (int jv = 0; jv < 16; ++jv) {
            bf16x8 w8 = row[jv];
            #pragma unroll
            for (int u = 0; u < 8; ++u) {
                float wf = (float)w8[u];
                a0h += wf * f0[jv * 8 + u];
                a1h += wf * f1[jv * 8 + u];
            }
        }
        hbuf[wb * 128 + co] = gelu_fast(a0h);
        hbuf[(wb + 2) * 128 + co] = gelu_fast(a1h);
    }
    __syncthreads();

    {
        int win = tid >> 6, j = tid & 63;     // 4 waves -> 4 windows
        const float* hb = hbuf + win * 128;
        float p = hw2[j] * hb[j] + hw2[j + 64] * hb[j + 64];
        #pragma unroll
        for (int off = 32; off > 0; off >>= 1) p += __shfl_down(p, off);
        if (j == 0) {
            float z = p + hb2[0];
            scores_tmp[b * NW + w0 + win] = 5.0f / (1.0f + expf(-z));
        }
    }
}

// ---------------------------------------------------------------------------
__global__ void finalize_kernel(const float* __restrict__ tmp, float* __restrict__ out) {
    int w = blockIdx.x * 256 + threadIdx.x;
    if (w < NW) {
        float s = 0.0f;
        #pragma unroll
        for (int b = 0; b < BATCH; ++b) s += tmp[b * NW + w];
        s *= 0.125f;
        out[w] = s;
        out[NW + w] = (s < 3.5f) ? 1.0f : 0.0f;
    }
}

// ---------------------------------------------------------------------------
extern "C" void kernel_launch(void* const* d_in, const int* in_sizes, int n_in,
                              void* d_out, int out_size, void* d_ws, size_t ws_size,
                              hipStream_t stream) {
    const float* lat  = (const float*)d_in[0];
    const float* c0w  = (const float*)d_in[1];
    const float* c0b  = (const float*)d_in[2];
    const float* c1w  = (const float*)d_in[3];
    const float* c1b  = (const float*)d_in[4];
    const float* c2w  = (const float*)d_in[5];
    const float* c2b  = (const float*)d_in[6];
    const float* hw1  = (const float*)d_in[7];
    const float* hb1  = (const float*)d_in[8];
    const float* hw2  = (const float*)d_in[9];
    const float* hb2  = (const float*)d_in[10];

    // workspace layout
    bf16* p0   = (bf16*)d_ws;                                 // 458752 B
    bf16* p1   = (bf16*)((char*)d_ws + 458752);               // 163840 B
    bf16* p2   = (bf16*)((char*)d_ws + 622592);               // 163840 B
    bf16* hw1b = (bf16*)((char*)d_ws + 786432);               //  32768 B
    float* tmp = (float*)((char*)d_ws + 819200);              //  32000 B

    prep_kernel<<<1600, 256, 0, stream>>>(c0w, c1w, c2w, hw1, p0, p1, p2, hw1b);
    critic_kernel<<<BATCH * (NW / 4), 256, 0, stream>>>(lat, p0, c0b, p1, c1b, p2, c2b,
                                                        hw1b, hb1, hw2, hb2, tmp);
    finalize_kernel<<<4, 256, 0, stream>>>(tmp, (float*)d_out);
}